// Round 1
// baseline (262.758 us; speedup 1.0000x reference)
//
#include <hip/hip_runtime.h>

// SSIM loss, fused separable implementation.
// B,C,H,W = 16,3,512,512 fixed by the reference. Window 11x11 Gaussian,
// separable: w1[i] = row-sum of the 2D window (since sum(w1)==1).

#define WSZ   11
#define RAD   5
#define TILE_W 32
#define TILE_H 32
#define IN_W  (TILE_W + 2*RAD)   // 42
#define IN_H  (TILE_H + 2*RAD)   // 42
#define BLOCK 256

__global__ __launch_bounds__(BLOCK) void ssim_tile_kernel(
    const float* __restrict__ pred,
    const float* __restrict__ target,
    const float* __restrict__ window,   // 11x11
    double* __restrict__ acc,
    int H, int W)
{
    __shared__ float sp[IN_H][IN_W];
    __shared__ float st[IN_H][IN_W];
    __shared__ float hb[5][IN_H][TILE_W];   // h-blurred p, t, p^2, t^2, p*t
    __shared__ float w1[WSZ];
    __shared__ float wavesum[BLOCK / 64];

    const int t = threadIdx.x;

    // Recover separable 1D window: row sums of the 2D window.
    if (t < WSZ) {
        float s = 0.f;
        #pragma unroll
        for (int j = 0; j < WSZ; ++j) s += window[t * WSZ + j];
        w1[t] = s;
    }

    const int tiles_x = W / TILE_W;
    const int tiles_y = H / TILE_H;
    const int tiles_per_img = tiles_x * tiles_y;
    const int img        = blockIdx.x / tiles_per_img;
    const int tid_in_img = blockIdx.x % tiles_per_img;
    const int tyi = tid_in_img / tiles_x;
    const int txi = tid_in_img % tiles_x;
    const int row0 = tyi * TILE_H - RAD;
    const int col0 = txi * TILE_W - RAD;

    const float* __restrict__ p = pred   + (size_t)img * H * W;
    const float* __restrict__ q = target + (size_t)img * H * W;

    // Stage input tile + halo; zero outside image (SAME zero padding).
    for (int l = t; l < IN_H * IN_W; l += BLOCK) {
        const int r = l / IN_W, c = l % IN_W;
        const int gr = row0 + r, gc = col0 + c;
        float pv = 0.f, tv = 0.f;
        if (gr >= 0 && gr < H && gc >= 0 && gc < W) {
            const size_t idx = (size_t)gr * W + gc;
            pv = p[idx];
            tv = q[idx];
        }
        sp[r][c] = pv;
        st[r][c] = tv;
    }
    __syncthreads();

    // Horizontal 11-tap pass for all 5 fields.
    for (int l = t; l < IN_H * TILE_W; l += BLOCK) {
        const int r = l / TILE_W, c = l % TILE_W;
        float s1 = 0.f, s2 = 0.f, s11 = 0.f, s22 = 0.f, s12 = 0.f;
        #pragma unroll
        for (int k = 0; k < WSZ; ++k) {
            const float w  = w1[k];
            const float pv = sp[r][c + k];
            const float tv = st[r][c + k];
            s1  += w * pv;
            s2  += w * tv;
            s11 += w * pv * pv;
            s22 += w * tv * tv;
            s12 += w * pv * tv;
        }
        hb[0][r][c] = s1;
        hb[1][r][c] = s2;
        hb[2][r][c] = s11;
        hb[3][r][c] = s22;
        hb[4][r][c] = s12;
    }
    __syncthreads();

    // Vertical 11-tap pass + SSIM per output pixel; accumulate locally.
    const float C1  = 1e-4f;   // (0.01*1)^2
    const float C2  = 9e-4f;   // (0.03*1)^2
    const float EPS = 1e-8f;
    float local = 0.f;
    for (int l = t; l < TILE_H * TILE_W; l += BLOCK) {
        const int r = l / TILE_W, c = l % TILE_W;
        float m1 = 0.f, m2 = 0.f, e11 = 0.f, e22 = 0.f, e12 = 0.f;
        #pragma unroll
        for (int k = 0; k < WSZ; ++k) {
            const float w = w1[k];
            m1  += w * hb[0][r + k][c];
            m2  += w * hb[1][r + k][c];
            e11 += w * hb[2][r + k][c];
            e22 += w * hb[3][r + k][c];
            e12 += w * hb[4][r + k][c];
        }
        const float m1sq = m1 * m1, m2sq = m2 * m2, m12 = m1 * m2;
        const float v1 = e11 - m1sq;          // sigma1_sq
        const float v2 = e22 - m2sq;          // sigma2_sq
        const float cv = e12 - m12;           // sigma12
        const float num = (2.f * m12 + C1) * (2.f * cv + C2);
        const float den = (m1sq + m2sq + C1) * (v1 + v2 + C2) + EPS;
        local += num / den;
    }

    // Wave (64-lane) shuffle reduce, then cross-wave via LDS.
    #pragma unroll
    for (int off = 32; off > 0; off >>= 1)
        local += __shfl_down(local, off, 64);
    const int lane = t & 63, wid = t >> 6;
    if (lane == 0) wavesum[wid] = local;
    __syncthreads();
    if (t == 0) {
        float s = 0.f;
        #pragma unroll
        for (int w = 0; w < BLOCK / 64; ++w) s += wavesum[w];
        atomicAdd(acc, (double)s);   // device-scope f64 atomic (native on gfx950)
    }
}

__global__ void ssim_finalize_kernel(const double* __restrict__ acc,
                                     float* __restrict__ out, double invN)
{
    out[0] = (float)(1.0 - acc[0] * invN);
}

extern "C" void kernel_launch(void* const* d_in, const int* in_sizes, int n_in,
                              void* d_out, int out_size, void* d_ws, size_t ws_size,
                              hipStream_t stream)
{
    const float* pred   = (const float*)d_in[0];
    const float* target = (const float*)d_in[1];
    const float* window = (const float*)d_in[2];
    float*  out = (float*)d_out;
    double* acc = (double*)d_ws;

    const int B = 16, C = 3, H = 512, W = 512;
    const int n_img = B * C;
    const int tiles = n_img * (H / TILE_H) * (W / TILE_W);   // 12288

    // d_ws is poisoned 0xAA before every timed launch: zero the accumulator.
    hipMemsetAsync(d_ws, 0, sizeof(double), stream);

    ssim_tile_kernel<<<tiles, BLOCK, 0, stream>>>(pred, target, window, acc, H, W);

    const double invN = 1.0 / ((double)n_img * H * W);
    ssim_finalize_kernel<<<1, 1, 0, stream>>>(acc, out, invN);
}